// Round 1
// baseline (287.798 us; speedup 1.0000x reference)
//
#include <hip/hip_runtime.h>

#define N_NODES 100000
#define DIM 128
#define NS 10
#define SCALE (1.0f / 11.0f)

// C[i][e] = sum_f X[i][f] * Wm[e][f]   (X: [M,128], Wm: [128,128], row-major)
// 128x128 output tile per block, 8x8 micro-tile per thread, fp32 VALU.
__global__ __launch_bounds__(256) void gemm_xwt(const float* __restrict__ X,
                                                const float* __restrict__ Wm,
                                                float* __restrict__ C, int M) {
    __shared__ float As[128][33];  // +1 pad: row-major, bank = (row + kk) % 32
    __shared__ float Ws[128][33];
    const int t = threadIdx.x;
    const int row0 = blockIdx.x * 128;
    const int tm = t >> 4;  // 0..15 -> rows 8*tm..8*tm+7
    const int tn = t & 15;  // 0..15 -> cols tn, tn+16, ..., tn+112
    float acc[8][8];
#pragma unroll
    for (int u = 0; u < 8; ++u)
#pragma unroll
        for (int v = 0; v < 8; ++v) acc[u][v] = 0.f;

    const int rr = t >> 3;  // 0..31
    const int cc = t & 7;   // 0..7

    for (int k0 = 0; k0 < DIM; k0 += 32) {
#pragma unroll
        for (int q = 0; q < 4; ++q) {
            const int r = rr + 32 * q;
            const int grow = row0 + r;
            float4 av = make_float4(0.f, 0.f, 0.f, 0.f);
            if (grow < M)
                av = *reinterpret_cast<const float4*>(X + (size_t)grow * DIM + k0 + 4 * cc);
            As[r][4 * cc + 0] = av.x;
            As[r][4 * cc + 1] = av.y;
            As[r][4 * cc + 2] = av.z;
            As[r][4 * cc + 3] = av.w;
            const float4 wv =
                *reinterpret_cast<const float4*>(Wm + (size_t)r * DIM + k0 + 4 * cc);
            Ws[r][4 * cc + 0] = wv.x;
            Ws[r][4 * cc + 1] = wv.y;
            Ws[r][4 * cc + 2] = wv.z;
            Ws[r][4 * cc + 3] = wv.w;
        }
        __syncthreads();
#pragma unroll 8
        for (int kk = 0; kk < 32; ++kk) {
            float a[8], b[8];
#pragma unroll
            for (int u = 0; u < 8; ++u) a[u] = As[8 * tm + u][kk];  // 4 banks, bcast
#pragma unroll
            for (int v = 0; v < 8; ++v) b[v] = Ws[tn + 16 * v][kk];  // 16 banks, bcast
#pragma unroll
            for (int u = 0; u < 8; ++u)
#pragma unroll
                for (int v = 0; v < 8; ++v) acc[u][v] += a[u] * b[v];
        }
        __syncthreads();
    }
#pragma unroll
    for (int u = 0; u < 8; ++u) {
        const int grow = row0 + 8 * tm + u;
        if (grow < M) {
#pragma unroll
            for (int v = 0; v < 8; ++v)
                C[(size_t)grow * DIM + tn + 16 * v] = acc[u][v];
        }
    }
}

// H[i][:] = relu((FW[i][:] + sum_s FW[adj[i][s]][:]) / 11)
// 8 rows per block; one 32-lane team per row; float4 per lane.
__global__ __launch_bounds__(256) void agg1_relu(const float* __restrict__ FW,
                                                 const int* __restrict__ adj,
                                                 float* __restrict__ H) {
    const int t = threadIdx.x;
    const int team = t >> 5;
    const int j = t & 31;
    const int i = blockIdx.x * 8 + team;  // 12500*8 == 100000, no guard needed
    int av = 0;
    if (j < NS) av = adj[(size_t)i * NS + j];
    float4 acc = *reinterpret_cast<const float4*>(FW + (size_t)i * DIM + 4 * j);  // self
#pragma unroll
    for (int s = 0; s < NS; ++s) {
        const int idx = __shfl(av, s, 32);
        const float4 v =
            *reinterpret_cast<const float4*>(FW + (size_t)idx * DIM + 4 * j);
        acc.x += v.x;
        acc.y += v.y;
        acc.z += v.z;
        acc.w += v.w;
    }
    acc.x = fmaxf(acc.x * SCALE, 0.f);
    acc.y = fmaxf(acc.y * SCALE, 0.f);
    acc.z = fmaxf(acc.z * SCALE, 0.f);
    acc.w = fmaxf(acc.w * SCALE, 0.f);
    *reinterpret_cast<float4*>(H + (size_t)i * DIM + 4 * j) = acc;
}

// out[e][b] = relu((G[n_b][e] + sum_s G[adj[n_b][s]][e]) / 11), n_b = nodes[b]
// 64 b's per block; LDS transpose so output writes are coalesced float4s.
__global__ __launch_bounds__(256) void agg2_trans(const float* __restrict__ G,
                                                  const int* __restrict__ adj,
                                                  const int* __restrict__ nodes,
                                                  float* __restrict__ out) {
    __shared__ float trans[DIM][65];  // bank = (e + bi) % 32 -> conflict-free
    __shared__ int idxs[64][12];
    const int t = threadIdx.x;
    const int b0 = blockIdx.x * 64;
    if (t < 64) {
        const int b = b0 + t;
        idxs[t][0] = (b < N_NODES) ? nodes[b] : 0;
    }
    __syncthreads();
    for (int l = t; l < 64 * NS; l += 256) {
        const int bi = l / NS;
        const int s = l - bi * NS;
        const int n = idxs[bi][0];
        idxs[bi][1 + s] = adj[(size_t)n * NS + s];
    }
    __syncthreads();
    const int team = t >> 5;
    const int j = t & 31;
#pragma unroll
    for (int biter = 0; biter < 8; ++biter) {
        const int bi = biter * 8 + team;
        float acc0 = 0.f, acc1 = 0.f, acc2 = 0.f, acc3 = 0.f;
        if (b0 + bi < N_NODES) {
            for (int s = 0; s <= NS; ++s) {
                const float* base = G + (size_t)idxs[bi][s] * DIM;
                acc0 += base[j];
                acc1 += base[j + 32];
                acc2 += base[j + 64];
                acc3 += base[j + 96];
            }
        }
        trans[j][bi] = fmaxf(acc0 * SCALE, 0.f);
        trans[j + 32][bi] = fmaxf(acc1 * SCALE, 0.f);
        trans[j + 64][bi] = fmaxf(acc2 * SCALE, 0.f);
        trans[j + 96][bi] = fmaxf(acc3 * SCALE, 0.f);
    }
    __syncthreads();
    const int erow = t >> 4;        // 0..15
    const int col4 = (t & 15) * 4;  // 0..60
    if (b0 + col4 < N_NODES) {      // N_NODES % 4 == 0 -> whole float4 valid
#pragma unroll
        for (int eit = 0; eit < 8; ++eit) {
            const int e = erow + 16 * eit;
            float4 v;
            v.x = trans[e][col4 + 0];
            v.y = trans[e][col4 + 1];
            v.z = trans[e][col4 + 2];
            v.w = trans[e][col4 + 3];
            *reinterpret_cast<float4*>(out + (size_t)e * N_NODES + b0 + col4) = v;
        }
    }
}

extern "C" void kernel_launch(void* const* d_in, const int* in_sizes, int n_in,
                              void* d_out, int out_size, void* d_ws, size_t ws_size,
                              hipStream_t stream) {
    const float* features = (const float*)d_in[0];
    const float* W1 = (const float*)d_in[1];
    const float* W2 = (const float*)d_in[2];
    const int* adj = (const int*)d_in[3];
    const int* nodes = (const int*)d_in[4];
    float* out = (float*)d_out;

    float* ws0 = (float*)d_ws;                      // FW1, then G (51.2 MB)
    float* ws1 = ws0 + (size_t)N_NODES * DIM;       // h1 (51.2 MB)

    const int gemm_blocks = (N_NODES + 127) / 128;  // 782

    // FW1 = features @ W1^T
    gemm_xwt<<<gemm_blocks, 256, 0, stream>>>(features, W1, ws0, N_NODES);
    // h1 = relu(mean(FW1[self ∪ adj]))
    agg1_relu<<<N_NODES / 8, 256, 0, stream>>>(ws0, adj, ws1);
    // G = h1 @ W2^T   (overwrites FW1, no longer needed)
    gemm_xwt<<<gemm_blocks, 256, 0, stream>>>(ws1, W2, ws0, N_NODES);
    // out[e][b] = relu(mean(G[nodes[b] ∪ adj[nodes[b]]]))[e]
    agg2_trans<<<(N_NODES + 63) / 64, 256, 0, stream>>>(ws0, adj, nodes, out);
}

// Round 2
// 206.871 us; speedup vs baseline: 1.3912x; 1.3912x over previous
//
#include <hip/hip_runtime.h>

#define N_NODES 100000
#define DIM 128
#define NS 10
#define SCALE (1.0f / 11.0f)

typedef unsigned int uint;
typedef unsigned short ushort;

__device__ inline float bl(uint u) {  // low bf16 -> float
    union { uint x; float f; } c; c.x = u << 16; return c.f;
}
__device__ inline float bh(uint u) {  // high bf16 -> float
    union { uint x; float f; } c; c.x = u & 0xFFFF0000u; return c.f;
}
__device__ inline uint f2b(float x) {  // float -> bf16 bits (RNE)
    union { float f; uint u; } c; c.f = x;
    return (c.u + 0x7FFFu + ((c.u >> 16) & 1u)) >> 16;
}

// C[i][e] = sum_f X[i][f] * Wm[e][f]; X fp32 [M,128], Wm fp32 [128,128], C bf16.
// 128x128 tile/block, 8x8 micro-tile/thread, fp32 VALU FMA, bf16 packed stores.
__global__ __launch_bounds__(256) void gemm_xwt(const float* __restrict__ X,
                                                const float* __restrict__ Wm,
                                                ushort* __restrict__ C, int M) {
    __shared__ float As[128][33];
    __shared__ float Ws[128][33];
    const int t = threadIdx.x;
    const int row0 = blockIdx.x * 128;
    const int tm = t >> 4;  // rows 8*tm..8*tm+7
    const int tn = t & 15;  // cols 4*tn..4*tn+3 and 64+4*tn..64+4*tn+3
    float acc[8][8];
#pragma unroll
    for (int u = 0; u < 8; ++u)
#pragma unroll
        for (int v = 0; v < 8; ++v) acc[u][v] = 0.f;

    const int rr = t >> 3;
    const int cc = t & 7;

    for (int k0 = 0; k0 < DIM; k0 += 32) {
#pragma unroll
        for (int q = 0; q < 4; ++q) {
            const int r = rr + 32 * q;
            const int grow = row0 + r;
            float4 av = make_float4(0.f, 0.f, 0.f, 0.f);
            if (grow < M)
                av = *reinterpret_cast<const float4*>(X + (size_t)grow * DIM + k0 + 4 * cc);
            As[r][4 * cc + 0] = av.x;
            As[r][4 * cc + 1] = av.y;
            As[r][4 * cc + 2] = av.z;
            As[r][4 * cc + 3] = av.w;
            const float4 wv =
                *reinterpret_cast<const float4*>(Wm + (size_t)r * DIM + k0 + 4 * cc);
            Ws[r][4 * cc + 0] = wv.x;
            Ws[r][4 * cc + 1] = wv.y;
            Ws[r][4 * cc + 2] = wv.z;
            Ws[r][4 * cc + 3] = wv.w;
        }
        __syncthreads();
#pragma unroll 8
        for (int kk = 0; kk < 32; ++kk) {
            float a[8], b[8];
#pragma unroll
            for (int u = 0; u < 8; ++u) a[u] = As[8 * tm + u][kk];
#pragma unroll
            for (int v = 0; v < 4; ++v) b[v] = Ws[4 * tn + v][kk];
#pragma unroll
            for (int v = 0; v < 4; ++v) b[4 + v] = Ws[64 + 4 * tn + v][kk];
#pragma unroll
            for (int u = 0; u < 8; ++u)
#pragma unroll
                for (int v = 0; v < 8; ++v) acc[u][v] += a[u] * b[v];
        }
        __syncthreads();
    }
#pragma unroll
    for (int u = 0; u < 8; ++u) {
        const int grow = row0 + 8 * tm + u;
        if (grow < M) {
            uint2 w0, w1;
            w0.x = f2b(acc[u][0]) | (f2b(acc[u][1]) << 16);
            w0.y = f2b(acc[u][2]) | (f2b(acc[u][3]) << 16);
            w1.x = f2b(acc[u][4]) | (f2b(acc[u][5]) << 16);
            w1.y = f2b(acc[u][6]) | (f2b(acc[u][7]) << 16);
            *reinterpret_cast<uint2*>(C + (size_t)grow * DIM + 4 * tn) = w0;
            *reinterpret_cast<uint2*>(C + (size_t)grow * DIM + 64 + 4 * tn) = w1;
        }
    }
}

// H[i][:] = relu((FW[i][:] + sum_s FW[adj[i][s]][:]) / 11); FW bf16, H fp32.
// 8 rows/block; 32-lane team per row; lane j handles elems {2j,2j+1,64+2j,64+2j+1}.
__global__ __launch_bounds__(256) void agg1_relu(const ushort* __restrict__ FW,
                                                 const int* __restrict__ adj,
                                                 float* __restrict__ H) {
    const int t = threadIdx.x;
    const int team = t >> 5;
    const int j = t & 31;
    const int i = blockIdx.x * 8 + team;  // 12500*8 == 100000
    int av = 0;
    if (j < NS) av = adj[(size_t)i * NS + j];
    const uint* self = reinterpret_cast<const uint*>(FW + (size_t)i * DIM);
    uint x = self[j], y = self[j + 32];
    float a0 = bl(x), a1 = bh(x), a2 = bl(y), a3 = bh(y);
#pragma unroll
    for (int s = 0; s < NS; ++s) {
        const int idx = __shfl(av, s, 32);
        const uint* rp = reinterpret_cast<const uint*>(FW + (size_t)idx * DIM);
        uint u = rp[j], v = rp[j + 32];
        a0 += bl(u); a1 += bh(u); a2 += bl(v); a3 += bh(v);
    }
    float2 w0, w1;
    w0.x = fmaxf(a0 * SCALE, 0.f);
    w0.y = fmaxf(a1 * SCALE, 0.f);
    w1.x = fmaxf(a2 * SCALE, 0.f);
    w1.y = fmaxf(a3 * SCALE, 0.f);
    *reinterpret_cast<float2*>(H + (size_t)i * DIM + 2 * j) = w0;
    *reinterpret_cast<float2*>(H + (size_t)i * DIM + 64 + 2 * j) = w1;
}

// out[e][b] = relu((G[n_b][e] + sum_s G[adj[n_b][s]][e]) / 11); G bf16, out fp32.
// 64 b's per block; two e-half passes through trans[64][65] (keeps LDS ~20KB).
__global__ __launch_bounds__(256) void agg2_trans(const ushort* __restrict__ G,
                                                  const int* __restrict__ adj,
                                                  const int* __restrict__ nodes,
                                                  float* __restrict__ out) {
    __shared__ float trans[64][65];
    __shared__ int idxs[64][12];
    const int t = threadIdx.x;
    const int b0 = blockIdx.x * 64;
    if (t < 64) idxs[t][0] = (b0 + t < N_NODES) ? nodes[b0 + t] : 0;
    __syncthreads();
    for (int l = t; l < 64 * NS; l += 256) {
        const int bi = l / NS;
        const int s = l - bi * NS;
        idxs[bi][1 + s] = adj[(size_t)idxs[bi][0] * NS + s];
    }
    __syncthreads();
    const int team = t >> 5;
    const int j = t & 31;
    const int erow = t >> 4;
    const int col4 = (t & 15) * 4;
#pragma unroll
    for (int p = 0; p < 2; ++p) {
        if (p) __syncthreads();  // protect trans from pass-0 readers
#pragma unroll
        for (int biter = 0; biter < 8; ++biter) {
            const int bi = biter * 8 + team;
            float a0 = 0.f, a1 = 0.f;
            for (int s = 0; s <= NS; ++s) {
                const uint* rp =
                    reinterpret_cast<const uint*>(G + (size_t)idxs[bi][s] * DIM);
                const uint u = rp[p * 32 + j];
                a0 += bl(u);
                a1 += bh(u);
            }
            trans[2 * j][bi] = fmaxf(a0 * SCALE, 0.f);
            trans[2 * j + 1][bi] = fmaxf(a1 * SCALE, 0.f);
        }
        __syncthreads();
        if (b0 + col4 < N_NODES) {  // N%4==0 -> whole float4 valid
#pragma unroll
            for (int eit = 0; eit < 4; ++eit) {
                const int el = erow + 16 * eit;
                const int e = p * 64 + el;
                float4 v;
                v.x = trans[el][col4 + 0];
                v.y = trans[el][col4 + 1];
                v.z = trans[el][col4 + 2];
                v.w = trans[el][col4 + 3];
                *reinterpret_cast<float4*>(out + (size_t)e * N_NODES + b0 + col4) = v;
            }
        }
    }
}

extern "C" void kernel_launch(void* const* d_in, const int* in_sizes, int n_in,
                              void* d_out, int out_size, void* d_ws, size_t ws_size,
                              hipStream_t stream) {
    const float* features = (const float*)d_in[0];
    const float* W1 = (const float*)d_in[1];
    const float* W2 = (const float*)d_in[2];
    const int* adj = (const int*)d_in[3];
    const int* nodes = (const int*)d_in[4];
    float* out = (float*)d_out;

    ushort* fw = (ushort*)d_ws;  // FW1 then G, bf16 (25.6 MB)
    float* h1 = (float*)((char*)d_ws + (size_t)N_NODES * DIM * sizeof(ushort));  // fp32 (51.2 MB)

    const int gemm_blocks = (N_NODES + 127) / 128;  // 782

    // FW1 = features @ W1^T  (bf16 out)
    gemm_xwt<<<gemm_blocks, 256, 0, stream>>>(features, W1, fw, N_NODES);
    // h1 = relu(mean(FW1[self ∪ adj]))  (fp32)
    agg1_relu<<<N_NODES / 8, 256, 0, stream>>>(fw, adj, h1);
    // G = h1 @ W2^T  (bf16 out, overwrites FW1)
    gemm_xwt<<<gemm_blocks, 256, 0, stream>>>(h1, W2, fw, N_NODES);
    // out[e][b] = relu(mean(G[nodes[b] ∪ adj[nodes[b]]]))[e]
    agg2_trans<<<(N_NODES + 63) / 64, 256, 0, stream>>>(fw, adj, nodes, out);
}

// Round 3
// 182.611 us; speedup vs baseline: 1.5760x; 1.1328x over previous
//
#include <hip/hip_runtime.h>

#define N_NODES 100000
#define DIM 128
#define NS 10
#define SCALE (1.0f / 11.0f)

typedef unsigned int uint;
typedef unsigned short ushort;
typedef __attribute__((ext_vector_type(8))) short bf16x8;
typedef __attribute__((ext_vector_type(4))) float f32x4;

__device__ inline float bl(uint u) {  // low bf16 bits -> float
    union { uint x; float f; } c; c.x = u << 16; return c.f;
}
__device__ inline uint f2b(float x) {  // float -> bf16 bits (RNE)
    union { float f; uint u; } c; c.f = x;
    return (c.u + 0x7FFFu + ((c.u >> 16) & 1u)) >> 16;
}

// Split W1,W2 (fp32 [128][128]) into bf16 hi/lo planes, once per launch.
__global__ __launch_bounds__(256) void wsplit(const float* __restrict__ W1,
                                              const float* __restrict__ W2,
                                              ushort* __restrict__ o) {
    const int i = blockIdx.x * 256 + threadIdx.x;  // 16384 total
    const float a = W1[i];
    uint h = f2b(a);
    o[i] = (ushort)h;
    o[16384 + i] = (ushort)f2b(a - bl(h));
    const float b = W2[i];
    h = f2b(b);
    o[32768 + i] = (ushort)h;
    o[49152 + i] = (ushort)f2b(b - bl(h));
}

// C[i][e] = sum_f A[i][f] * W[e][f], A:[M,128] fp32 (SPLITA=0) or hi/lo bf16
// planes (SPLITA=1), W pre-split hi/lo bf16 planes. bf16x3 emulation:
// hi*hi + lo*hi + hi*lo via mfma_f32_16x16x32_bf16, fp32 accum. C bf16.
// 256 thr = 4 waves; wave handles 32 rows x 128 cols (2 row-tiles x 8 col-tiles).
// No LDS: fragments loaded directly from global (rows read once; W L1/L2-hot).
template <bool SPLITA>
__global__ __launch_bounds__(256, 2) void gemm_mfma(const float* __restrict__ A32,
                                                    const ushort* __restrict__ Ahi,
                                                    const ushort* __restrict__ Alo,
                                                    const ushort* __restrict__ Whi,
                                                    const ushort* __restrict__ Wlo,
                                                    ushort* __restrict__ C, int M) {
    const int lane = threadIdx.x & 63;
    const int wave = threadIdx.x >> 6;
    const int row0 = blockIdx.x * 128 + wave * 32;
    const int m16 = lane & 15;          // row/col within 16-tile
    const int kh = (lane >> 4) * 8;     // k sub-offset 0/8/16/24

    f32x4 acc[2][8];
#pragma unroll
    for (int rt = 0; rt < 2; ++rt)
#pragma unroll
        for (int ct = 0; ct < 8; ++ct) acc[rt][ct] = (f32x4){0.f, 0.f, 0.f, 0.f};

    int rowc[2];
#pragma unroll
    for (int rt = 0; rt < 2; ++rt) {
        const int r = row0 + rt * 16 + m16;
        rowc[rt] = r < M ? r : M - 1;  // clamp; stores guarded below
    }

#pragma unroll
    for (int ks = 0; ks < 4; ++ks) {
        const int k0 = ks * 32 + kh;
        bf16x8 ahi[2], alo[2];
#pragma unroll
        for (int rt = 0; rt < 2; ++rt) {
            if (SPLITA) {
                ahi[rt] = *reinterpret_cast<const bf16x8*>(Ahi + (size_t)rowc[rt] * DIM + k0);
                alo[rt] = *reinterpret_cast<const bf16x8*>(Alo + (size_t)rowc[rt] * DIM + k0);
            } else {
                const float* ap = A32 + (size_t)rowc[rt] * DIM + k0;
                const float4 x0 = *reinterpret_cast<const float4*>(ap);
                const float4 x1 = *reinterpret_cast<const float4*>(ap + 4);
                const float xs[8] = {x0.x, x0.y, x0.z, x0.w, x1.x, x1.y, x1.z, x1.w};
#pragma unroll
                for (int j = 0; j < 8; ++j) {
                    const uint h = f2b(xs[j]);
                    ahi[rt][j] = (short)h;
                    alo[rt][j] = (short)f2b(xs[j] - bl(h));
                }
            }
        }
#pragma unroll
        for (int ct = 0; ct < 8; ++ct) {
            const size_t woff = (size_t)(ct * 16 + m16) * DIM + k0;
            const bf16x8 bhi = *reinterpret_cast<const bf16x8*>(Whi + woff);
            const bf16x8 blo = *reinterpret_cast<const bf16x8*>(Wlo + woff);
#pragma unroll
            for (int rt = 0; rt < 2; ++rt) {
                acc[rt][ct] = __builtin_amdgcn_mfma_f32_16x16x32_bf16(ahi[rt], bhi, acc[rt][ct], 0, 0, 0);
                acc[rt][ct] = __builtin_amdgcn_mfma_f32_16x16x32_bf16(alo[rt], bhi, acc[rt][ct], 0, 0, 0);
                acc[rt][ct] = __builtin_amdgcn_mfma_f32_16x16x32_bf16(ahi[rt], blo, acc[rt][ct], 0, 0, 0);
            }
        }
    }

    // C/D layout (16x16x32): col = lane&15, row = (lane>>4)*4 + reg
    const int rowadd = (lane >> 4) * 4;
#pragma unroll
    for (int rt = 0; rt < 2; ++rt) {
#pragma unroll
        for (int r4 = 0; r4 < 4; ++r4) {
            const int grow = row0 + rt * 16 + rowadd + r4;
            if (grow < M) {
#pragma unroll
                for (int ct = 0; ct < 8; ++ct)
                    C[(size_t)grow * DIM + ct * 16 + m16] = (ushort)f2b(acc[rt][ct][r4]);
            }
        }
    }
}

// H = relu(mean(FW[self U adj])); FW bf16, H written as hi/lo bf16 planes.
// 8 rows/block; 32-lane team per row; lane j handles elems {2j,2j+1,64+2j,64+2j+1}.
__global__ __launch_bounds__(256) void agg1_relu(const ushort* __restrict__ FW,
                                                 const int* __restrict__ adj,
                                                 ushort* __restrict__ Hhi,
                                                 ushort* __restrict__ Hlo) {
    const int t = threadIdx.x;
    const int team = t >> 5;
    const int j = t & 31;
    const int i = blockIdx.x * 8 + team;  // 12500*8 == 100000
    int av = 0;
    if (j < NS) av = adj[(size_t)i * NS + j];
    const uint* self = reinterpret_cast<const uint*>(FW + (size_t)i * DIM);
    uint x = self[j], y = self[j + 32];
    float a0 = bl(x), a1 = bl(x >> 16), a2 = bl(y), a3 = bl(y >> 16);
#pragma unroll
    for (int s = 0; s < NS; ++s) {
        const int idx = __shfl(av, s, 32);
        const uint* rp = reinterpret_cast<const uint*>(FW + (size_t)idx * DIM);
        const uint u = rp[j], v = rp[j + 32];
        a0 += bl(u); a1 += bl(u >> 16); a2 += bl(v); a3 += bl(v >> 16);
    }
    a0 = fmaxf(a0 * SCALE, 0.f);
    a1 = fmaxf(a1 * SCALE, 0.f);
    a2 = fmaxf(a2 * SCALE, 0.f);
    a3 = fmaxf(a3 * SCALE, 0.f);
    const uint h0 = f2b(a0), h1 = f2b(a1), h2 = f2b(a2), h3 = f2b(a3);
    const uint l0 = f2b(a0 - bl(h0)), l1 = f2b(a1 - bl(h1));
    const uint l2 = f2b(a2 - bl(h2)), l3 = f2b(a3 - bl(h3));
    uint* ph = reinterpret_cast<uint*>(Hhi);
    uint* pl = reinterpret_cast<uint*>(Hlo);
    ph[i * 64 + j] = h0 | (h1 << 16);
    ph[i * 64 + 32 + j] = h2 | (h3 << 16);
    pl[i * 64 + j] = l0 | (l1 << 16);
    pl[i * 64 + 32 + j] = l2 | (l3 << 16);
}

// out[e][b] = relu(mean(G[nodes[b] U adj[nodes[b]]]))[e]; G bf16, out fp32.
__global__ __launch_bounds__(256) void agg2_trans(const ushort* __restrict__ G,
                                                  const int* __restrict__ adj,
                                                  const int* __restrict__ nodes,
                                                  float* __restrict__ out) {
    __shared__ float trans[64][65];
    __shared__ int idxs[64][12];
    const int t = threadIdx.x;
    const int b0 = blockIdx.x * 64;
    if (t < 64) idxs[t][0] = (b0 + t < N_NODES) ? nodes[b0 + t] : 0;
    __syncthreads();
    for (int l = t; l < 64 * NS; l += 256) {
        const int bi = l / NS;
        const int s = l - bi * NS;
        idxs[bi][1 + s] = adj[(size_t)idxs[bi][0] * NS + s];
    }
    __syncthreads();
    const int team = t >> 5;
    const int j = t & 31;
    const int erow = t >> 4;
    const int col4 = (t & 15) * 4;
#pragma unroll
    for (int p = 0; p < 2; ++p) {
        if (p) __syncthreads();
#pragma unroll
        for (int biter = 0; biter < 8; ++biter) {
            const int bi = biter * 8 + team;
            float a0 = 0.f, a1 = 0.f;
            for (int s = 0; s <= NS; ++s) {
                const uint* rp =
                    reinterpret_cast<const uint*>(G + (size_t)idxs[bi][s] * DIM);
                const uint u = rp[p * 32 + j];
                a0 += bl(u);
                a1 += bl(u >> 16);
            }
            trans[2 * j][bi] = fmaxf(a0 * SCALE, 0.f);
            trans[2 * j + 1][bi] = fmaxf(a1 * SCALE, 0.f);
        }
        __syncthreads();
        if (b0 + col4 < N_NODES) {
#pragma unroll
            for (int eit = 0; eit < 4; ++eit) {
                const int el = erow + 16 * eit;
                const int e = p * 64 + el;
                float4 v;
                v.x = trans[el][col4 + 0];
                v.y = trans[el][col4 + 1];
                v.z = trans[el][col4 + 2];
                v.w = trans[el][col4 + 3];
                *reinterpret_cast<float4*>(out + (size_t)e * N_NODES + b0 + col4) = v;
            }
        }
    }
}

extern "C" void kernel_launch(void* const* d_in, const int* in_sizes, int n_in,
                              void* d_out, int out_size, void* d_ws, size_t ws_size,
                              hipStream_t stream) {
    const float* features = (const float*)d_in[0];
    const float* W1 = (const float*)d_in[1];
    const float* W2 = (const float*)d_in[2];
    const int* adj = (const int*)d_in[3];
    const int* nodes = (const int*)d_in[4];
    float* out = (float*)d_out;

    const size_t NE = (size_t)N_NODES * DIM;  // 12.8M elems
    ushort* fw = (ushort*)d_ws;               // FW1 then G, bf16 (25.6 MB)
    ushort* h1hi = fw + NE;                   // 25.6 MB
    ushort* h1lo = h1hi + NE;                 // 25.6 MB
    ushort* wpl = h1lo + NE;                  // 4 x 32 KB planes
    ushort* w1hi = wpl;
    ushort* w1lo = wpl + 16384;
    ushort* w2hi = wpl + 32768;
    ushort* w2lo = wpl + 49152;

    const int gemm_blocks = (N_NODES + 127) / 128;  // 782

    wsplit<<<64, 256, 0, stream>>>(W1, W2, wpl);
    // FW1 = features @ W1^T (bf16x3 MFMA, in-register feature split)
    gemm_mfma<false><<<gemm_blocks, 256, 0, stream>>>(features, nullptr, nullptr,
                                                      w1hi, w1lo, fw, N_NODES);
    // h1 = relu(mean(FW1[self U adj])) -> hi/lo planes
    agg1_relu<<<N_NODES / 8, 256, 0, stream>>>(fw, adj, h1hi, h1lo);
    // G = h1 @ W2^T (bf16x3 MFMA, pre-split A)
    gemm_mfma<true><<<gemm_blocks, 256, 0, stream>>>(nullptr, h1hi, h1lo,
                                                     w2hi, w2lo, fw, N_NODES);
    // out[e][b] = relu(mean(G[nodes[b] U adj[nodes[b]]]))[e]
    agg2_trans<<<(N_NODES + 63) / 64, 256, 0, stream>>>(fw, adj, nodes, out);
}

// Round 4
// 178.584 us; speedup vs baseline: 1.6116x; 1.0225x over previous
//
#include <hip/hip_runtime.h>

#define N_NODES 100000
#define DIM 128
#define NS 10
#define SCALE (1.0f / 11.0f)

typedef unsigned int uint;
typedef unsigned short ushort;
typedef __attribute__((ext_vector_type(8))) short bf16x8;
typedef __attribute__((ext_vector_type(4))) float f32x4;

__device__ inline float bl(uint u) {  // bf16 bits (low 16) -> float
    union { uint x; float f; } c; c.x = u << 16; return c.f;
}
__device__ inline uint f2b(float x) {  // float -> bf16 bits (RNE)
    union { float f; uint u; } c; c.f = x;
    return (c.u + 0x7FFFu + ((c.u >> 16) & 1u)) >> 16;
}

// Split W1,W2 (fp32 [128][128]) into bf16 hi/lo planes, once per launch.
__global__ __launch_bounds__(256) void wsplit(const float* __restrict__ W1,
                                              const float* __restrict__ W2,
                                              ushort* __restrict__ o) {
    const int i = blockIdx.x * 256 + threadIdx.x;  // 16384 total
    const float a = W1[i];
    uint h = f2b(a);
    o[i] = (ushort)h;
    o[16384 + i] = (ushort)f2b(a - bl(h));
    const float b = W2[i];
    h = f2b(b);
    o[32768 + i] = (ushort)h;
    o[49152 + i] = (ushort)f2b(b - bl(h));
}

__device__ inline void split8(const float4& a, const float4& b, bf16x8& h, bf16x8& l) {
    const float xs[8] = {a.x, a.y, a.z, a.w, b.x, b.y, b.z, b.w};
#pragma unroll
    for (int j = 0; j < 8; ++j) {
        const uint hb = f2b(xs[j]);
        h[j] = (short)hb;
        l[j] = (short)f2b(xs[j] - bl(hb));
    }
}

// C[i][e] = sum_f X[i][f]*W1[e][f]; X fp32 split in-register (hi/lo bf16),
// bf16x3 MFMA (hi*Whi + lo*Whi + hi*Wlo), C bf16 [M][128].
// Block = 32 rows; 4 waves, wave owns 32 cols (2 ct-tiles); W frags in VGPRs.
__global__ __launch_bounds__(256) void gemm1(const float* __restrict__ X,
                                             const ushort* __restrict__ Whi,
                                             const ushort* __restrict__ Wlo,
                                             ushort* __restrict__ C) {
    const int lane = threadIdx.x & 63;
    const int wave = threadIdx.x >> 6;
    const int m16 = lane & 15;
    const int kh = (lane >> 4) * 8;
    const int r0 = blockIdx.x * 32;  // 3125*32 == 100000, no guards
    const int ct0 = wave * 2;

    bf16x8 wh[2][4], wl[2][4];
#pragma unroll
    for (int c = 0; c < 2; ++c)
#pragma unroll
        for (int ks = 0; ks < 4; ++ks) {
            const size_t woff = (size_t)((ct0 + c) * 16 + m16) * DIM + ks * 32 + kh;
            wh[c][ks] = *reinterpret_cast<const bf16x8*>(Whi + woff);
            wl[c][ks] = *reinterpret_cast<const bf16x8*>(Wlo + woff);
        }

    f32x4 acc[2][2];
#pragma unroll
    for (int rt = 0; rt < 2; ++rt)
#pragma unroll
        for (int c = 0; c < 2; ++c) acc[rt][c] = (f32x4){0.f, 0.f, 0.f, 0.f};

    const float* ap0 = X + (size_t)(r0 + m16) * DIM + kh;
    const float* ap1 = ap0 + 16 * DIM;

#pragma unroll
    for (int ks = 0; ks < 4; ++ks) {
        const float4 x0a = *reinterpret_cast<const float4*>(ap0 + ks * 32);
        const float4 x0b = *reinterpret_cast<const float4*>(ap0 + ks * 32 + 4);
        const float4 x1a = *reinterpret_cast<const float4*>(ap1 + ks * 32);
        const float4 x1b = *reinterpret_cast<const float4*>(ap1 + ks * 32 + 4);
        bf16x8 ah[2], al[2];
        split8(x0a, x0b, ah[0], al[0]);
        split8(x1a, x1b, ah[1], al[1]);
#pragma unroll
        for (int c = 0; c < 2; ++c)
#pragma unroll
            for (int rt = 0; rt < 2; ++rt) {
                acc[rt][c] = __builtin_amdgcn_mfma_f32_16x16x32_bf16(ah[rt], wh[c][ks], acc[rt][c], 0, 0, 0);
                acc[rt][c] = __builtin_amdgcn_mfma_f32_16x16x32_bf16(al[rt], wh[c][ks], acc[rt][c], 0, 0, 0);
                acc[rt][c] = __builtin_amdgcn_mfma_f32_16x16x32_bf16(ah[rt], wl[c][ks], acc[rt][c], 0, 0, 0);
            }
    }

    const int rowadd = (lane >> 4) * 4;  // C/D: col=lane&15, row=(lane>>4)*4+reg
#pragma unroll
    for (int rt = 0; rt < 2; ++rt)
#pragma unroll
        for (int r4 = 0; r4 < 4; ++r4) {
            const size_t row = r0 + rt * 16 + rowadd + r4;
#pragma unroll
            for (int c = 0; c < 2; ++c)
                C[row * DIM + (ct0 + c) * 16 + m16] = (ushort)f2b(acc[rt][c][r4]);
        }
}

// out[e][b] = relu(sum_f P[b][f]*W2[e][f]); P bf16, W2 hi/lo (2 MFMAs),
// fp32 transposed store: lane's 4 acc regs are 4 consecutive b at fixed e -> float4.
__global__ __launch_bounds__(256) void gemm2t(const ushort* __restrict__ P,
                                              const ushort* __restrict__ Whi,
                                              const ushort* __restrict__ Wlo,
                                              float* __restrict__ out) {
    const int lane = threadIdx.x & 63;
    const int wave = threadIdx.x >> 6;
    const int m16 = lane & 15;
    const int kh = (lane >> 4) * 8;
    const int r0 = blockIdx.x * 32;
    const int ct0 = wave * 2;

    bf16x8 wh[2][4], wl[2][4];
#pragma unroll
    for (int c = 0; c < 2; ++c)
#pragma unroll
        for (int ks = 0; ks < 4; ++ks) {
            const size_t woff = (size_t)((ct0 + c) * 16 + m16) * DIM + ks * 32 + kh;
            wh[c][ks] = *reinterpret_cast<const bf16x8*>(Whi + woff);
            wl[c][ks] = *reinterpret_cast<const bf16x8*>(Wlo + woff);
        }

    f32x4 acc[2][2];
#pragma unroll
    for (int rt = 0; rt < 2; ++rt)
#pragma unroll
        for (int c = 0; c < 2; ++c) acc[rt][c] = (f32x4){0.f, 0.f, 0.f, 0.f};

    const ushort* ap0 = P + (size_t)(r0 + m16) * DIM + kh;
    const ushort* ap1 = ap0 + 16 * DIM;

#pragma unroll
    for (int ks = 0; ks < 4; ++ks) {
        const bf16x8 a0 = *reinterpret_cast<const bf16x8*>(ap0 + ks * 32);
        const bf16x8 a1 = *reinterpret_cast<const bf16x8*>(ap1 + ks * 32);
#pragma unroll
        for (int c = 0; c < 2; ++c) {
            acc[0][c] = __builtin_amdgcn_mfma_f32_16x16x32_bf16(a0, wh[c][ks], acc[0][c], 0, 0, 0);
            acc[0][c] = __builtin_amdgcn_mfma_f32_16x16x32_bf16(a0, wl[c][ks], acc[0][c], 0, 0, 0);
            acc[1][c] = __builtin_amdgcn_mfma_f32_16x16x32_bf16(a1, wh[c][ks], acc[1][c], 0, 0, 0);
            acc[1][c] = __builtin_amdgcn_mfma_f32_16x16x32_bf16(a1, wl[c][ks], acc[1][c], 0, 0, 0);
        }
    }

    const int rowadd = (lane >> 4) * 4;
#pragma unroll
    for (int rt = 0; rt < 2; ++rt)
#pragma unroll
        for (int c = 0; c < 2; ++c) {
            float4 v;
            v.x = fmaxf(acc[rt][c][0], 0.f);
            v.y = fmaxf(acc[rt][c][1], 0.f);
            v.z = fmaxf(acc[rt][c][2], 0.f);
            v.w = fmaxf(acc[rt][c][3], 0.f);
            const int e = (ct0 + c) * 16 + m16;
            const int b = r0 + rt * 16 + rowadd;
            *reinterpret_cast<float4*>(out + (size_t)e * N_NODES + b) = v;
        }
}

// H[i] = relu(mean(FW[{i} U adj[i]])); FW bf16, H bf16.
// 8 rows/block; 32-lane team/row; lane j: elems {2j,2j+1,64+2j,64+2j+1}.
__global__ __launch_bounds__(256) void agg1(const ushort* __restrict__ FW,
                                            const int* __restrict__ adj,
                                            ushort* __restrict__ H) {
    const int t = threadIdx.x;
    const int team = t >> 5;
    const int j = t & 31;
    const int i = blockIdx.x * 8 + team;  // 12500*8 == 100000
    int av = 0;
    if (j < NS) av = adj[(size_t)i * NS + j];
    const uint* self = reinterpret_cast<const uint*>(FW + (size_t)i * DIM);
    const uint x = self[j], y = self[j + 32];
    float a0 = bl(x), a1 = bl(x >> 16), a2 = bl(y), a3 = bl(y >> 16);
#pragma unroll
    for (int s = 0; s < NS; ++s) {
        const int idx = __shfl(av, s, 32);
        const uint* rp = reinterpret_cast<const uint*>(FW + (size_t)idx * DIM);
        const uint u = rp[j], v = rp[j + 32];
        a0 += bl(u); a1 += bl(u >> 16); a2 += bl(v); a3 += bl(v >> 16);
    }
    a0 = fmaxf(a0 * SCALE, 0.f);
    a1 = fmaxf(a1 * SCALE, 0.f);
    a2 = fmaxf(a2 * SCALE, 0.f);
    a3 = fmaxf(a3 * SCALE, 0.f);
    uint* ph = reinterpret_cast<uint*>(H);
    ph[(size_t)i * 64 + j] = f2b(a0) | (f2b(a1) << 16);
    ph[(size_t)i * 64 + 32 + j] = f2b(a2) | (f2b(a3) << 16);
}

// P[i] = mean(H[{n} U adj[n]]), n = nodes[i]; H bf16, P bf16 (no relu).
__global__ __launch_bounds__(256) void agg2b(const ushort* __restrict__ H,
                                             const int* __restrict__ adj,
                                             const int* __restrict__ nodes,
                                             ushort* __restrict__ P) {
    const int t = threadIdx.x;
    const int team = t >> 5;
    const int j = t & 31;
    const int i = blockIdx.x * 8 + team;
    const int n = nodes[i];
    int av = 0;
    if (j < NS) av = adj[(size_t)n * NS + j];
    const uint* self = reinterpret_cast<const uint*>(H + (size_t)n * DIM);
    const uint x = self[j], y = self[j + 32];
    float a0 = bl(x), a1 = bl(x >> 16), a2 = bl(y), a3 = bl(y >> 16);
#pragma unroll
    for (int s = 0; s < NS; ++s) {
        const int idx = __shfl(av, s, 32);
        const uint* rp = reinterpret_cast<const uint*>(H + (size_t)idx * DIM);
        const uint u = rp[j], v = rp[j + 32];
        a0 += bl(u); a1 += bl(u >> 16); a2 += bl(v); a3 += bl(v >> 16);
    }
    a0 *= SCALE; a1 *= SCALE; a2 *= SCALE; a3 *= SCALE;
    uint* pp = reinterpret_cast<uint*>(P);
    pp[(size_t)i * 64 + j] = f2b(a0) | (f2b(a1) << 16);
    pp[(size_t)i * 64 + 32 + j] = f2b(a2) | (f2b(a3) << 16);
}

extern "C" void kernel_launch(void* const* d_in, const int* in_sizes, int n_in,
                              void* d_out, int out_size, void* d_ws, size_t ws_size,
                              hipStream_t stream) {
    const float* features = (const float*)d_in[0];
    const float* W1 = (const float*)d_in[1];
    const float* W2 = (const float*)d_in[2];
    const int* adj = (const int*)d_in[3];
    const int* nodes = (const int*)d_in[4];
    float* out = (float*)d_out;

    const size_t NE = (size_t)N_NODES * DIM;  // 12.8M elems
    ushort* fw = (ushort*)d_ws;   // FW1, later reused as P (25.6 MB)
    ushort* h1 = fw + NE;         // h1 bf16 (25.6 MB)
    ushort* wpl = h1 + NE;        // 4 x 32 KB W planes
    ushort* w1hi = wpl;
    ushort* w1lo = wpl + 16384;
    ushort* w2hi = wpl + 32768;
    ushort* w2lo = wpl + 49152;

    wsplit<<<64, 256, 0, stream>>>(W1, W2, wpl);
    // FW1 = features @ W1^T (bf16x3 MFMA, register-resident W)
    gemm1<<<N_NODES / 32, 256, 0, stream>>>(features, w1hi, w1lo, fw);
    // h1 = relu(mean(FW1[self U adj]))
    agg1<<<N_NODES / 8, 256, 0, stream>>>(fw, adj, h1);
    // P = mean(h1[nodes U adj[nodes]])  (reuses fw buffer)
    agg2b<<<N_NODES / 8, 256, 0, stream>>>(h1, adj, nodes, fw);
    // out[e][b] = relu(P @ W2^T) transposed store
    gemm2t<<<N_NODES / 32, 256, 0, stream>>>(fw, w2hi, w2lo, out);
}

// Round 5
// 153.642 us; speedup vs baseline: 1.8732x; 1.1623x over previous
//
#include <hip/hip_runtime.h>

#define N_NODES 100000
#define DIM 128
#define NS 10
#define SCALE (1.0f / 11.0f)

typedef unsigned int uint;
typedef unsigned short ushort;
typedef __attribute__((ext_vector_type(8))) short bf16x8;
typedef __attribute__((ext_vector_type(4))) float f32x4;

__device__ inline float bl(uint u) {  // bf16 bits (low 16) -> float
    union { uint x; float f; } c; c.x = u << 16; return c.f;
}
__device__ inline uint f2b(float x) {  // float -> bf16 bits (RNE)
    union { float f; uint u; } c; c.f = x;
    return (c.u + 0x7FFFu + ((c.u >> 16) & 1u)) >> 16;
}

// Split W1,W2 (fp32 [128][128]) into bf16 hi/lo planes, once per launch.
__global__ __launch_bounds__(256) void wsplit(const float* __restrict__ W1,
                                              const float* __restrict__ W2,
                                              ushort* __restrict__ o) {
    const int i = blockIdx.x * 256 + threadIdx.x;  // 16384 total
    const float a = W1[i];
    uint h = f2b(a);
    o[i] = (ushort)h;
    o[16384 + i] = (ushort)f2b(a - bl(h));
    const float b = W2[i];
    h = f2b(b);
    o[32768 + i] = (ushort)h;
    o[49152 + i] = (ushort)f2b(b - bl(h));
}

// gemm1: C[r][e] = sum_k X[r][k]*W1[e][k]; bf16x3 MFMA (Xhi*Whi + Xlo*Whi +
// Xhi*Wlo), fp32 accum, C bf16. Operand-SWAPPED (W = A-operand, X = B-operand)
// so a lane's 4 acc regs are 4 consecutive e -> one 8B packed store.
// Block = 32-row strip x 128 e; X staged to LDS in fragment layout (hi/lo
// split at stage time); W frags (2 e-tiles/wave) held in VGPRs.
__global__ __launch_bounds__(256, 2) void gemm1(const float* __restrict__ X,
                                                const ushort* __restrict__ Whi,
                                                const ushort* __restrict__ Wlo,
                                                ushort* __restrict__ C) {
    // fragment layout: group g = bt*4+ks (bt=row-tile, ks=k-step), 64 lanes x 16B
    __shared__ __align__(16) ushort lds[8192];  // hi [0,4096), lo [4096,8192)
    const int t = threadIdx.x;
    const int lane = t & 63;
    const int wave = t >> 6;
    const int m16 = lane & 15;
    const int kq = lane >> 4;
    const int r0 = blockIdx.x * 32;  // 3125*32 == 100000, no guards

    // Stage slots: v in {t, t+256}; v -> bt=v>>8, ks=(v>>6)&3, ln=v&63.
    // Slot holds X[row=r0+bt*16+(ln&15)][k=32*ks+8*(ln>>4) .. +8) as hi/lo bf16.
    const int v0 = t, v1 = t + 256;
    const int ln0 = v0 & 63, ln1 = v1 & 63;
    const float* s0 = X + (size_t)(r0 + (v0 >> 8) * 16 + (ln0 & 15)) * DIM +
                      ((v0 >> 6) & 3) * 32 + (ln0 >> 4) * 8;
    const float* s1 = X + (size_t)(r0 + (v1 >> 8) * 16 + (ln1 & 15)) * DIM +
                      ((v1 >> 6) & 3) * 32 + (ln1 >> 4) * 8;
    // issue all 4 stage loads up front (independent, in flight together)
    const float4 f00 = *(const float4*)(s0);
    const float4 f01 = *(const float4*)(s0 + 4);
    const float4 f10 = *(const float4*)(s1);
    const float4 f11 = *(const float4*)(s1 + 4);

    // W frags (A-operand): e-tile et = 2*wave + c; row e = et*16+m16, k-off 8*kq
    bf16x8 wh[2][4], wl[2][4];
#pragma unroll
    for (int c = 0; c < 2; ++c)
#pragma unroll
        for (int ks = 0; ks < 4; ++ks) {
            const size_t off = (size_t)((2 * wave + c) * 16 + m16) * DIM + ks * 32 + kq * 8;
            wh[c][ks] = *(const bf16x8*)(Whi + off);
            wl[c][ks] = *(const bf16x8*)(Wlo + off);
        }

    {
        const float xs[8] = {f00.x, f00.y, f00.z, f00.w, f01.x, f01.y, f01.z, f01.w};
        bf16x8 hi, lo;
#pragma unroll
        for (int j = 0; j < 8; ++j) {
            const uint hb = f2b(xs[j]);
            hi[j] = (short)hb;
            lo[j] = (short)f2b(xs[j] - bl(hb));
        }
        *(bf16x8*)(lds + (v0 >> 6) * 512 + ln0 * 8) = hi;
        *(bf16x8*)(lds + 4096 + (v0 >> 6) * 512 + ln0 * 8) = lo;
    }
    {
        const float xs[8] = {f10.x, f10.y, f10.z, f10.w, f11.x, f11.y, f11.z, f11.w};
        bf16x8 hi, lo;
#pragma unroll
        for (int j = 0; j < 8; ++j) {
            const uint hb = f2b(xs[j]);
            hi[j] = (short)hb;
            lo[j] = (short)f2b(xs[j] - bl(hb));
        }
        *(bf16x8*)(lds + (v1 >> 6) * 512 + ln1 * 8) = hi;
        *(bf16x8*)(lds + 4096 + (v1 >> 6) * 512 + ln1 * 8) = lo;
    }
    __syncthreads();

    f32x4 acc[2][2];  // [bt][c]
#pragma unroll
    for (int bt = 0; bt < 2; ++bt)
#pragma unroll
        for (int c = 0; c < 2; ++c) acc[bt][c] = (f32x4){0.f, 0.f, 0.f, 0.f};

#pragma unroll
    for (int ks = 0; ks < 4; ++ks) {
#pragma unroll
        for (int bt = 0; bt < 2; ++bt) {
            const int g = bt * 4 + ks;
            const bf16x8 xh = *(const bf16x8*)(lds + g * 512 + lane * 8);
            const bf16x8 xl = *(const bf16x8*)(lds + 4096 + g * 512 + lane * 8);
#pragma unroll
            for (int c = 0; c < 2; ++c) {
                acc[bt][c] = __builtin_amdgcn_mfma_f32_16x16x32_bf16(wh[c][ks], xh, acc[bt][c], 0, 0, 0);
                acc[bt][c] = __builtin_amdgcn_mfma_f32_16x16x32_bf16(wl[c][ks], xh, acc[bt][c], 0, 0, 0);
                acc[bt][c] = __builtin_amdgcn_mfma_f32_16x16x32_bf16(wh[c][ks], xl, acc[bt][c], 0, 0, 0);
            }
        }
    }

    // D layout: col(m16) = X-row, row(kq*4+reg) = e -> 4 consecutive e per lane
#pragma unroll
    for (int bt = 0; bt < 2; ++bt) {
        const size_t row = (size_t)(r0 + bt * 16 + m16);
#pragma unroll
        for (int c = 0; c < 2; ++c) {
            uint2 w;
            w.x = f2b(acc[bt][c][0]) | (f2b(acc[bt][c][1]) << 16);
            w.y = f2b(acc[bt][c][2]) | (f2b(acc[bt][c][3]) << 16);
            *(uint2*)(C + row * DIM + (2 * wave + c) * 16 + kq * 4) = w;
        }
    }
}

// gemm2t: out[e][b] = relu(sum_k P[b][k]*W2[e][k]); P bf16 (A-operand, staged
// in LDS fragment layout), W2 hi/lo = B-operand in VGPRs (2 MFMAs/term pair).
// acc regs = 4 consecutive b at fixed e -> coalesced float4 stores to [E][B].
__global__ __launch_bounds__(256, 2) void gemm2t(const ushort* __restrict__ P,
                                                 const ushort* __restrict__ Whi,
                                                 const ushort* __restrict__ Wlo,
                                                 float* __restrict__ out) {
    __shared__ __align__(16) ushort lds[4096];  // 8 groups x 64 lanes x 8 bf16
    const int t = threadIdx.x;
    const int lane = t & 63;
    const int wave = t >> 6;
    const int m16 = lane & 15;
    const int kq = lane >> 4;
    const int r0 = blockIdx.x * 32;

    const int v0 = t, v1 = t + 256;
    const int ln0 = v0 & 63, ln1 = v1 & 63;
    const ushort* s0 = P + (size_t)(r0 + (v0 >> 8) * 16 + (ln0 & 15)) * DIM +
                       ((v0 >> 6) & 3) * 32 + (ln0 >> 4) * 8;
    const ushort* s1 = P + (size_t)(r0 + (v1 >> 8) * 16 + (ln1 & 15)) * DIM +
                       ((v1 >> 6) & 3) * 32 + (ln1 >> 4) * 8;
    const bf16x8 p0 = *(const bf16x8*)(s0);
    const bf16x8 p1 = *(const bf16x8*)(s1);

    bf16x8 wh[2][4], wl[2][4];
#pragma unroll
    for (int c = 0; c < 2; ++c)
#pragma unroll
        for (int ks = 0; ks < 4; ++ks) {
            const size_t off = (size_t)((2 * wave + c) * 16 + m16) * DIM + ks * 32 + kq * 8;
            wh[c][ks] = *(const bf16x8*)(Whi + off);
            wl[c][ks] = *(const bf16x8*)(Wlo + off);
        }

    *(bf16x8*)(lds + (v0 >> 6) * 512 + ln0 * 8) = p0;
    *(bf16x8*)(lds + (v1 >> 6) * 512 + ln1 * 8) = p1;
    __syncthreads();

    f32x4 acc[2][2];  // [bt][c]
#pragma unroll
    for (int bt = 0; bt < 2; ++bt)
#pragma unroll
        for (int c = 0; c < 2; ++c) acc[bt][c] = (f32x4){0.f, 0.f, 0.f, 0.f};

#pragma unroll
    for (int ks = 0; ks < 4; ++ks) {
#pragma unroll
        for (int bt = 0; bt < 2; ++bt) {
            const bf16x8 pa = *(const bf16x8*)(lds + (bt * 4 + ks) * 512 + lane * 8);
#pragma unroll
            for (int c = 0; c < 2; ++c) {
                acc[bt][c] = __builtin_amdgcn_mfma_f32_16x16x32_bf16(pa, wh[c][ks], acc[bt][c], 0, 0, 0);
                acc[bt][c] = __builtin_amdgcn_mfma_f32_16x16x32_bf16(pa, wl[c][ks], acc[bt][c], 0, 0, 0);
            }
        }
    }

    // D layout: col(m16) = e (B-side), row(kq*4+reg) = b (A-side)
#pragma unroll
    for (int bt = 0; bt < 2; ++bt) {
        const int b = r0 + bt * 16 + kq * 4;
#pragma unroll
        for (int c = 0; c < 2; ++c) {
            const int e = (2 * wave + c) * 16 + m16;
            float4 v;
            v.x = fmaxf(acc[bt][c][0], 0.f);
            v.y = fmaxf(acc[bt][c][1], 0.f);
            v.z = fmaxf(acc[bt][c][2], 0.f);
            v.w = fmaxf(acc[bt][c][3], 0.f);
            *(float4*)(out + (size_t)e * N_NODES + b) = v;
        }
    }
}

// H[i] = relu(mean(FW[{i} U adj[i]])); FW bf16, H bf16.
// 8 rows/block; 32-lane team/row; lane j owns elems 4j..4j+3 (one uint2/row).
__global__ __launch_bounds__(256) void agg1(const ushort* __restrict__ FW,
                                            const int* __restrict__ adj,
                                            ushort* __restrict__ H) {
    const int t = threadIdx.x;
    const int team = t >> 5;
    const int j = t & 31;
    const int i = blockIdx.x * 8 + team;  // 12500*8 == 100000
    int av = 0;
    if (j < NS) av = adj[(size_t)i * NS + j];
    const uint2 x = ((const uint2*)(FW + (size_t)i * DIM))[j];
    float a0 = bl(x.x), a1 = bl(x.x >> 16), a2 = bl(x.y), a3 = bl(x.y >> 16);
#pragma unroll
    for (int s = 0; s < NS; ++s) {
        const int idx = __shfl(av, s, 32);
        const uint2 u = ((const uint2*)(FW + (size_t)idx * DIM))[j];
        a0 += bl(u.x); a1 += bl(u.x >> 16); a2 += bl(u.y); a3 += bl(u.y >> 16);
    }
    a0 = fmaxf(a0 * SCALE, 0.f);
    a1 = fmaxf(a1 * SCALE, 0.f);
    a2 = fmaxf(a2 * SCALE, 0.f);
    a3 = fmaxf(a3 * SCALE, 0.f);
    uint2 w;
    w.x = f2b(a0) | (f2b(a1) << 16);
    w.y = f2b(a2) | (f2b(a3) << 16);
    ((uint2*)(H + (size_t)i * DIM))[j] = w;
}

// P[i] = mean(H[{n} U adj[n]]), n = nodes[i]; H bf16, P bf16 (no relu).
__global__ __launch_bounds__(256) void agg2b(const ushort* __restrict__ H,
                                             const int* __restrict__ adj,
                                             const int* __restrict__ nodes,
                                             ushort* __restrict__ P) {
    const int t = threadIdx.x;
    const int team = t >> 5;
    const int j = t & 31;
    const int i = blockIdx.x * 8 + team;
    const int n = nodes[i];
    int av = 0;
    if (j < NS) av = adj[(size_t)n * NS + j];
    const uint2 x = ((const uint2*)(H + (size_t)n * DIM))[j];
    float a0 = bl(x.x), a1 = bl(x.x >> 16), a2 = bl(x.y), a3 = bl(x.y >> 16);
#pragma unroll
    for (int s = 0; s < NS; ++s) {
        const int idx = __shfl(av, s, 32);
        const uint2 u = ((const uint2*)(H + (size_t)idx * DIM))[j];
        a0 += bl(u.x); a1 += bl(u.x >> 16); a2 += bl(u.y); a3 += bl(u.y >> 16);
    }
    a0 *= SCALE; a1 *= SCALE; a2 *= SCALE; a3 *= SCALE;
    uint2 w;
    w.x = f2b(a0) | (f2b(a1) << 16);
    w.y = f2b(a2) | (f2b(a3) << 16);
    ((uint2*)(P + (size_t)i * DIM))[j] = w;
}

extern "C" void kernel_launch(void* const* d_in, const int* in_sizes, int n_in,
                              void* d_out, int out_size, void* d_ws, size_t ws_size,
                              hipStream_t stream) {
    const float* features = (const float*)d_in[0];
    const float* W1 = (const float*)d_in[1];
    const float* W2 = (const float*)d_in[2];
    const int* adj = (const int*)d_in[3];
    const int* nodes = (const int*)d_in[4];
    float* out = (float*)d_out;

    const size_t NE = (size_t)N_NODES * DIM;  // 12.8M elems
    ushort* fw = (ushort*)d_ws;   // FW1, later reused as P (25.6 MB)
    ushort* h1 = fw + NE;         // h1 bf16 (25.6 MB)
    ushort* wpl = h1 + NE;        // 4 x 32 KB W planes
    ushort* w1hi = wpl;
    ushort* w1lo = wpl + 16384;
    ushort* w2hi = wpl + 32768;
    ushort* w2lo = wpl + 49152;

    wsplit<<<64, 256, 0, stream>>>(W1, W2, wpl);
    // FW1 = features @ W1^T (bf16x3 MFMA, LDS fragment staging)
    gemm1<<<N_NODES / 32, 256, 0, stream>>>(features, w1hi, w1lo, fw);
    // h1 = relu(mean(FW1[self U adj]))
    agg1<<<N_NODES / 8, 256, 0, stream>>>(fw, adj, h1);
    // P = mean(h1[nodes U adj[nodes]])  (reuses fw buffer)
    agg2b<<<N_NODES / 8, 256, 0, stream>>>(h1, adj, nodes, fw);
    // out[e][b] = relu(P @ W2^T), coalesced transposed store
    gemm2t<<<N_NODES / 32, 256, 0, stream>>>(fw, w2hi, w2lo, out);
}

// Round 6
// 144.943 us; speedup vs baseline: 1.9856x; 1.0600x over previous
//
#include <hip/hip_runtime.h>

#define N_NODES 100000
#define DIM 128
#define NS 10
#define SCALE (1.0f / 11.0f)

typedef unsigned int uint;
typedef unsigned short ushort;
typedef __attribute__((ext_vector_type(8))) short bf16x8;
typedef __attribute__((ext_vector_type(4))) float f32x4;

__device__ inline float bl(uint u) {  // bf16 bits (low 16) -> float
    union { uint x; float f; } c; c.x = u << 16; return c.f;
}
__device__ inline uint f2b(float x) {  // float -> bf16 bits (RNE)
    union { float f; uint u; } c; c.f = x;
    return (c.u + 0x7FFFu + ((c.u >> 16) & 1u)) >> 16;
}

// Split W1,W2 (fp32 [128][128]) into bf16 hi/lo planes, once per launch.
__global__ __launch_bounds__(256) void wsplit(const float* __restrict__ W1,
                                              const float* __restrict__ W2,
                                              ushort* __restrict__ o) {
    const int i = blockIdx.x * 256 + threadIdx.x;  // 16384 total
    const float a = W1[i];
    uint h = f2b(a);
    o[i] = (ushort)h;
    o[16384 + i] = (ushort)f2b(a - bl(h));
    const float b = W2[i];
    h = f2b(b);
    o[32768 + i] = (ushort)h;
    o[49152 + i] = (ushort)f2b(b - bl(h));
}

// gemm1: C[r][e] = sum_k X[r][k]*W1[e][k]; bf16x3 MFMA (Xhi*Whi + Xlo*Whi +
// Xhi*Wlo), fp32 accum, C bf16. Operand-SWAPPED (W = A-operand) so a lane's
// 4 acc regs are 4 consecutive e -> one 8B packed store.
// Block = 32-row strip x 128 e; X staged to LDS in fragment layout.
__global__ __launch_bounds__(256, 2) void gemm1(const float* __restrict__ X,
                                                const ushort* __restrict__ Whi,
                                                const ushort* __restrict__ Wlo,
                                                ushort* __restrict__ C) {
    __shared__ __align__(16) ushort lds[8192];  // hi [0,4096), lo [4096,8192)
    const int t = threadIdx.x;
    const int lane = t & 63;
    const int wave = t >> 6;
    const int m16 = lane & 15;
    const int kq = lane >> 4;
    const int r0 = blockIdx.x * 32;  // 3125*32 == 100000, no guards

    const int v0 = t, v1 = t + 256;
    const int ln0 = v0 & 63, ln1 = v1 & 63;
    const float* s0 = X + (size_t)(r0 + (v0 >> 8) * 16 + (ln0 & 15)) * DIM +
                      ((v0 >> 6) & 3) * 32 + (ln0 >> 4) * 8;
    const float* s1 = X + (size_t)(r0 + (v1 >> 8) * 16 + (ln1 & 15)) * DIM +
                      ((v1 >> 6) & 3) * 32 + (ln1 >> 4) * 8;
    const float4 f00 = *(const float4*)(s0);
    const float4 f01 = *(const float4*)(s0 + 4);
    const float4 f10 = *(const float4*)(s1);
    const float4 f11 = *(const float4*)(s1 + 4);

    bf16x8 wh[2][4], wl[2][4];
#pragma unroll
    for (int c = 0; c < 2; ++c)
#pragma unroll
        for (int ks = 0; ks < 4; ++ks) {
            const size_t off = (size_t)((2 * wave + c) * 16 + m16) * DIM + ks * 32 + kq * 8;
            wh[c][ks] = *(const bf16x8*)(Whi + off);
            wl[c][ks] = *(const bf16x8*)(Wlo + off);
        }

    {
        const float xs[8] = {f00.x, f00.y, f00.z, f00.w, f01.x, f01.y, f01.z, f01.w};
        bf16x8 hi, lo;
#pragma unroll
        for (int j = 0; j < 8; ++j) {
            const uint hb = f2b(xs[j]);
            hi[j] = (short)hb;
            lo[j] = (short)f2b(xs[j] - bl(hb));
        }
        *(bf16x8*)(lds + (v0 >> 6) * 512 + ln0 * 8) = hi;
        *(bf16x8*)(lds + 4096 + (v0 >> 6) * 512 + ln0 * 8) = lo;
    }
    {
        const float xs[8] = {f10.x, f10.y, f10.z, f10.w, f11.x, f11.y, f11.z, f11.w};
        bf16x8 hi, lo;
#pragma unroll
        for (int j = 0; j < 8; ++j) {
            const uint hb = f2b(xs[j]);
            hi[j] = (short)hb;
            lo[j] = (short)f2b(xs[j] - bl(hb));
        }
        *(bf16x8*)(lds + (v1 >> 6) * 512 + ln1 * 8) = hi;
        *(bf16x8*)(lds + 4096 + (v1 >> 6) * 512 + ln1 * 8) = lo;
    }
    __syncthreads();

    f32x4 acc[2][2];  // [bt][c]
#pragma unroll
    for (int bt = 0; bt < 2; ++bt)
#pragma unroll
        for (int c = 0; c < 2; ++c) acc[bt][c] = (f32x4){0.f, 0.f, 0.f, 0.f};

#pragma unroll
    for (int ks = 0; ks < 4; ++ks) {
#pragma unroll
        for (int bt = 0; bt < 2; ++bt) {
            const int g = bt * 4 + ks;
            const bf16x8 xh = *(const bf16x8*)(lds + g * 512 + lane * 8);
            const bf16x8 xl = *(const bf16x8*)(lds + 4096 + g * 512 + lane * 8);
#pragma unroll
            for (int c = 0; c < 2; ++c) {
                acc[bt][c] = __builtin_amdgcn_mfma_f32_16x16x32_bf16(wh[c][ks], xh, acc[bt][c], 0, 0, 0);
                acc[bt][c] = __builtin_amdgcn_mfma_f32_16x16x32_bf16(wl[c][ks], xh, acc[bt][c], 0, 0, 0);
                acc[bt][c] = __builtin_amdgcn_mfma_f32_16x16x32_bf16(wh[c][ks], xl, acc[bt][c], 0, 0, 0);
            }
        }
    }

    // D layout: col(m16) = X-row, row(kq*4+reg) = e -> 4 consecutive e per lane
#pragma unroll
    for (int bt = 0; bt < 2; ++bt) {
        const size_t row = (size_t)(r0 + bt * 16 + m16);
#pragma unroll
        for (int c = 0; c < 2; ++c) {
            uint2 w;
            w.x = f2b(acc[bt][c][0]) | (f2b(acc[bt][c][1]) << 16);
            w.y = f2b(acc[bt][c][2]) | (f2b(acc[bt][c][3]) << 16);
            *(uint2*)(C + row * DIM + (2 * wave + c) * 16 + kq * 4) = w;
        }
    }
}

// agg1: H[i] = relu(mean(FW[{i} U adj[i]])); FW bf16, H bf16.
// 32 rows/block; 16-lane team per row-pair; lane j owns 16B chunk j.
// All 11 row-loads issued into u[] before accumulation (max MLP).
__global__ __launch_bounds__(256) void agg1(const ushort* __restrict__ FW,
                                            const int* __restrict__ adj,
                                            ushort* __restrict__ H) {
    __shared__ int idx_lds[320];
    const int t = threadIdx.x;
    const int r0 = blockIdx.x * 32;  // 3125 blocks
    for (int l = t; l < 320; l += 256)
        idx_lds[l] = adj[(size_t)r0 * NS + l];  // rows r0..r0+31 contiguous
    __syncthreads();
    const int team = t >> 4;
    const int j = t & 15;
#pragma unroll
    for (int rp = 0; rp < 2; ++rp) {
        const int ri = team * 2 + rp;
        const int row = r0 + ri;
        uint4 u[11];
        u[0] = *(const uint4*)(FW + (size_t)row * DIM + j * 8);
#pragma unroll
        for (int s = 0; s < NS; ++s)
            u[1 + s] = *(const uint4*)(FW + (size_t)idx_lds[ri * NS + s] * DIM + j * 8);
        float a[8];
#pragma unroll
        for (int k = 0; k < 8; ++k) a[k] = 0.f;
#pragma unroll
        for (int s = 0; s < 11; ++s) {
            a[0] += bl(u[s].x); a[1] += bl(u[s].x >> 16);
            a[2] += bl(u[s].y); a[3] += bl(u[s].y >> 16);
            a[4] += bl(u[s].z); a[5] += bl(u[s].z >> 16);
            a[6] += bl(u[s].w); a[7] += bl(u[s].w >> 16);
        }
        uint4 w;
        w.x = f2b(fmaxf(a[0] * SCALE, 0.f)) | (f2b(fmaxf(a[1] * SCALE, 0.f)) << 16);
        w.y = f2b(fmaxf(a[2] * SCALE, 0.f)) | (f2b(fmaxf(a[3] * SCALE, 0.f)) << 16);
        w.z = f2b(fmaxf(a[4] * SCALE, 0.f)) | (f2b(fmaxf(a[5] * SCALE, 0.f)) << 16);
        w.w = f2b(fmaxf(a[6] * SCALE, 0.f)) | (f2b(fmaxf(a[7] * SCALE, 0.f)) << 16);
        *(uint4*)(H + (size_t)row * DIM + j * 8) = w;
    }
}

// gemm2f: fused layer-2. Per block: gather+mean 32 P-rows from H (fp32 accum),
// write bf16 into LDS fragment layout, then MFMA (P=A, W2 hi/lo=B) and
// transposed relu store: out[e][b], lane's 4 acc regs = 4 consecutive b.
__global__ __launch_bounds__(256, 2) void gemm2f(const ushort* __restrict__ H,
                                                 const int* __restrict__ adj,
                                                 const int* __restrict__ nodes,
                                                 const ushort* __restrict__ Whi,
                                                 const ushort* __restrict__ Wlo,
                                                 float* __restrict__ out) {
    __shared__ __align__(16) ushort plds[4096];  // P fragment layout, 8 KB
    __shared__ int idx_lds[32 * 11];
    const int t = threadIdx.x;
    const int lane = t & 63;
    const int wave = t >> 6;
    const int m16w = lane & 15;
    const int kq = lane >> 4;
    const int r0 = blockIdx.x * 32;

    if (t < 32) idx_lds[t * 11] = nodes[r0 + t];

    // W frags (B-operand): issued before barriers, loop-invariant
    bf16x8 wh[2][4], wl[2][4];
#pragma unroll
    for (int c = 0; c < 2; ++c)
#pragma unroll
        for (int ks = 0; ks < 4; ++ks) {
            const size_t off = (size_t)((2 * wave + c) * 16 + m16w) * DIM + ks * 32 + kq * 8;
            wh[c][ks] = *(const bf16x8*)(Whi + off);
            wl[c][ks] = *(const bf16x8*)(Wlo + off);
        }
    __syncthreads();
    for (int l = t; l < 320; l += 256) {
        const int bi = l / 10;
        const int s = l - bi * 10;
        idx_lds[bi * 11 + 1 + s] = adj[(size_t)idx_lds[bi * 11] * NS + s];
    }
    __syncthreads();

    const int team = t >> 4;
    const int j = t & 15;
#pragma unroll
    for (int rp = 0; rp < 2; ++rp) {
        const int ri = team * 2 + rp;
        uint4 u[11];
#pragma unroll
        for (int s = 0; s < 11; ++s)
            u[s] = *(const uint4*)(H + (size_t)idx_lds[ri * 11 + s] * DIM + j * 8);
        float a[8];
#pragma unroll
        for (int k = 0; k < 8; ++k) a[k] = 0.f;
#pragma unroll
        for (int s = 0; s < 11; ++s) {
            a[0] += bl(u[s].x); a[1] += bl(u[s].x >> 16);
            a[2] += bl(u[s].y); a[3] += bl(u[s].y >> 16);
            a[4] += bl(u[s].z); a[5] += bl(u[s].z >> 16);
            a[6] += bl(u[s].w); a[7] += bl(u[s].w >> 16);
        }
        bf16x8 pw;
#pragma unroll
        for (int k = 0; k < 8; ++k) pw[k] = (short)f2b(a[k] * SCALE);
        // fragment slot: row ri -> bt=ri>>4, m16=ri&15; chunk j -> ks=j>>2, kq=j&3
        const int bt = ri >> 4;
        const int m16 = ri & 15;
        *(bf16x8*)(plds + (bt * 4 + (j >> 2)) * 512 + ((j & 3) * 16 + m16) * 8) = pw;
    }
    __syncthreads();

    f32x4 acc[2][2];  // [bt][c]
#pragma unroll
    for (int bt = 0; bt < 2; ++bt)
#pragma unroll
        for (int c = 0; c < 2; ++c) acc[bt][c] = (f32x4){0.f, 0.f, 0.f, 0.f};

#pragma unroll
    for (int ks = 0; ks < 4; ++ks) {
#pragma unroll
        for (int bt = 0; bt < 2; ++bt) {
            const bf16x8 pa = *(const bf16x8*)(plds + (bt * 4 + ks) * 512 + lane * 8);
#pragma unroll
            for (int c = 0; c < 2; ++c) {
                acc[bt][c] = __builtin_amdgcn_mfma_f32_16x16x32_bf16(pa, wh[c][ks], acc[bt][c], 0, 0, 0);
                acc[bt][c] = __builtin_amdgcn_mfma_f32_16x16x32_bf16(pa, wl[c][ks], acc[bt][c], 0, 0, 0);
            }
        }
    }

    // D layout: row(kq*4+reg) = b (A-side), col(m16w) = e (B-side)
#pragma unroll
    for (int bt = 0; bt < 2; ++bt) {
        const int b = r0 + bt * 16 + kq * 4;
#pragma unroll
        for (int c = 0; c < 2; ++c) {
            const int e = (2 * wave + c) * 16 + m16w;
            float4 v;
            v.x = fmaxf(acc[bt][c][0], 0.f);
            v.y = fmaxf(acc[bt][c][1], 0.f);
            v.z = fmaxf(acc[bt][c][2], 0.f);
            v.w = fmaxf(acc[bt][c][3], 0.f);
            *(float4*)(out + (size_t)e * N_NODES + b) = v;
        }
    }
}

extern "C" void kernel_launch(void* const* d_in, const int* in_sizes, int n_in,
                              void* d_out, int out_size, void* d_ws, size_t ws_size,
                              hipStream_t stream) {
    const float* features = (const float*)d_in[0];
    const float* W1 = (const float*)d_in[1];
    const float* W2 = (const float*)d_in[2];
    const int* adj = (const int*)d_in[3];
    const int* nodes = (const int*)d_in[4];
    float* out = (float*)d_out;

    const size_t NE = (size_t)N_NODES * DIM;  // 12.8M elems
    ushort* fw = (ushort*)d_ws;   // FW1 bf16 (25.6 MB)
    ushort* h1 = fw + NE;         // h1 bf16 (25.6 MB)
    ushort* wpl = h1 + NE;        // 4 x 32 KB W planes
    ushort* w1hi = wpl;
    ushort* w1lo = wpl + 16384;
    ushort* w2hi = wpl + 32768;
    ushort* w2lo = wpl + 49152;

    wsplit<<<64, 256, 0, stream>>>(W1, W2, wpl);
    // FW1 = features @ W1^T (bf16x3 MFMA, LDS fragment staging)
    gemm1<<<N_NODES / 32, 256, 0, stream>>>(features, w1hi, w1lo, fw);
    // h1 = relu(mean(FW1[self U adj]))
    agg1<<<N_NODES / 32, 256, 0, stream>>>(fw, adj, h1);
    // out = relu((mean h1[nodes U adj[nodes]]) @ W2^T), fused gather+GEMM
    gemm2f<<<N_NODES / 32, 256, 0, stream>>>(h1, adj, nodes, w2hi, w2lo, out);
}